// Round 1
// baseline (341.095 us; speedup 1.0000x reference)
//
#include <hip/hip_runtime.h>
#include <hip/hip_bf16.h>

typedef unsigned short ushort_t;
typedef __attribute__((ext_vector_type(8))) short short8;
typedef __attribute__((ext_vector_type(4))) float f32x4;

#define B_    4
#define T_    2048
#define D_    768
#define NH_   12
#define DH_   64
#define MTOT  8192    /* B*T */
#define KDIM  768

__device__ __forceinline__ ushort_t f2bf(float f) {
  union { float f; unsigned u; } c; c.f = f;
  unsigned u = c.u;
  return (ushort_t)((u + 0x7FFFu + ((u >> 16) & 1u)) >> 16);
}

__device__ __forceinline__ void gload_lds16(const void* g, void* l) {
  __builtin_amdgcn_global_load_lds(
      (const __attribute__((address_space(1))) unsigned int*)g,
      (__attribute__((address_space(3))) unsigned int*)l, 16, 0, 0);
}

// ---------------------------------------------------------------- converts
__global__ void cvt_bf16_vec(const float* __restrict__ in,
                             ushort_t* __restrict__ out, int n4) {
  int i = blockIdx.x * blockDim.x + threadIdx.x;
  if (i >= n4) return;
  float4 v = ((const float4*)in)[i];
  ushort4 o;
  o.x = f2bf(v.x); o.y = f2bf(v.y); o.z = f2bf(v.z); o.w = f2bf(v.w);
  ((ushort4*)out)[i] = o;
}

// in [R][C] fp32 -> out [C][R] bf16
__global__ void transpose_cvt(const float* __restrict__ in,
                              ushort_t* __restrict__ out, int R, int C) {
  __shared__ float tile[32][33];
  int c0 = blockIdx.x * 32, r0 = blockIdx.y * 32;
  int tx = threadIdx.x, ty = threadIdx.y;
#pragma unroll
  for (int j = 0; j < 32; j += 8)
    tile[ty + j][tx] = in[(size_t)(r0 + ty + j) * C + c0 + tx];
  __syncthreads();
#pragma unroll
  for (int j = 0; j < 32; j += 8)
    out[(size_t)(c0 + ty + j) * R + r0 + tx] = f2bf(tile[tx][ty + j]);
}

// ---------------------------------------------------------------- GEMM core
// C[128,128] tile at (m0,n0): A[M][K] bf16 row-major, BT[N][K] bf16 row-major.
// 4 waves as 2x2, each wave 64x64 = 4x4 frags of 16x16, K-step 32. m97 structure.
__device__ __forceinline__ void gemm128_mainloop(
    const ushort_t* __restrict__ A, const ushort_t* __restrict__ BT,
    int m0, int n0, ushort_t* lds, f32x4 acc[4][4]) {
  const int t = threadIdx.x;
  const int l = t & 63;
  const int w = t >> 6;
  const int wm = w >> 1, wn = w & 1;
  // staging: chunk c = s*256 + t covers 8 bf16; tile row = c>>2, col = (c&3)*8
  const int c0 = t, c1 = t + 256;
  const ushort_t* ga0 = A + (size_t)(m0 + (c0 >> 2)) * KDIM + ((c0 & 3) << 3);
  const ushort_t* ga1 = A + (size_t)(m0 + (c1 >> 2)) * KDIM + ((c1 & 3) << 3);
  const ushort_t* gb0 = BT + (size_t)(n0 + (c0 >> 2)) * KDIM + ((c0 & 3) << 3);
  const ushort_t* gb1 = BT + (size_t)(n0 + (c1 >> 2)) * KDIM + ((c1 & 3) << 3);
  ushort_t* la0 = lds + (0 * 256 + w * 64) * 8;
  ushort_t* la1 = lds + (1 * 256 + w * 64) * 8;
  ushort_t* lb0 = lds + 4096 + (0 * 256 + w * 64) * 8;
  ushort_t* lb1 = lds + 4096 + (1 * 256 + w * 64) * 8;
  const int frag_off = ((l & 15) * 32) + ((l >> 4) * 8);

  for (int k0 = 0; k0 < KDIM; k0 += 32) {
    gload_lds16(ga0 + k0, la0);
    gload_lds16(ga1 + k0, la1);
    gload_lds16(gb0 + k0, lb0);
    gload_lds16(gb1 + k0, lb1);
    __syncthreads();
    short8 af[4], bfv[4];
#pragma unroll
    for (int mt = 0; mt < 4; ++mt)
      af[mt] = *(const short8*)&lds[(wm * 64 + mt * 16) * 32 + frag_off];
#pragma unroll
    for (int nt = 0; nt < 4; ++nt)
      bfv[nt] = *(const short8*)&lds[4096 + (wn * 64 + nt * 16) * 32 + frag_off];
#pragma unroll
    for (int mt = 0; mt < 4; ++mt)
#pragma unroll
      for (int nt = 0; nt < 4; ++nt)
        acc[mt][nt] = __builtin_amdgcn_mfma_f32_16x16x32_bf16(
            af[mt], bfv[nt], acc[mt][nt], 0, 0, 0);
    __syncthreads();
  }
}

// GEMM1: x_bf [8192][768] @ wT_attn[2304][768]^T + b_attn
// n in [0,768) -> q_bf (ws, bf16, [B][NH][T][DH])
// n in [768,1536) -> k fp32 to d_out region  (same head layout)
// n in [1536,2304) -> v fp32 to d_out region
__global__ __launch_bounds__(256) void gemm_qkv_kernel(
    const ushort_t* __restrict__ xbf, const ushort_t* __restrict__ wT,
    const float* __restrict__ bias, ushort_t* __restrict__ qbf,
    float* __restrict__ kout, float* __restrict__ vout) {
  __shared__ ushort_t lds[8192];
  int bid = blockIdx.x;
  int m0 = (bid & 63) << 7;
  int n0 = (bid >> 6) << 7;
  f32x4 acc[4][4];
  f32x4 zero = {0.f, 0.f, 0.f, 0.f};
#pragma unroll
  for (int a = 0; a < 4; ++a)
#pragma unroll
    for (int b = 0; b < 4; ++b) acc[a][b] = zero;
  gemm128_mainloop(xbf, wT, m0, n0, lds, acc);

  const int l = threadIdx.x & 63, w = threadIdx.x >> 6;
  const int wm = w >> 1, wn = w & 1;
  const int sec = n0 / 768;  // tile lies fully inside one of q/k/v
#pragma unroll
  for (int nt = 0; nt < 4; ++nt) {
    int n = n0 + wn * 64 + nt * 16 + (l & 15);
    float bv = bias[n];
    int nn = n - sec * 768;
    int h = nn >> 6, dh = nn & 63;
#pragma unroll
    for (int mt = 0; mt < 4; ++mt) {
#pragma unroll
      for (int r = 0; r < 4; ++r) {
        int m = m0 + wm * 64 + mt * 16 + ((l >> 4) << 2) + r;
        int b = m >> 11, tt = m & 2047;
        float val = acc[mt][nt][r] + bv;
        size_t idx = ((size_t)((b * NH_ + h) * T_ + tt) << 6) + dh;
        if (sec == 0)      qbf[idx]  = f2bf(val);
        else if (sec == 1) kout[idx] = val;
        else               vout[idx] = val;
      }
    }
  }
}

// GEMM2: attn_bf [8192][768] @ wT_proj[768][768]^T + b_proj -> out fp32
__global__ __launch_bounds__(256) void gemm_proj_kernel(
    const ushort_t* __restrict__ abf, const ushort_t* __restrict__ wT,
    const float* __restrict__ bias, float* __restrict__ out) {
  __shared__ ushort_t lds[8192];
  int bid = blockIdx.x;
  int m0 = (bid & 63) << 7;
  int n0 = (bid >> 6) << 7;
  f32x4 acc[4][4];
  f32x4 zero = {0.f, 0.f, 0.f, 0.f};
#pragma unroll
  for (int a = 0; a < 4; ++a)
#pragma unroll
    for (int b = 0; b < 4; ++b) acc[a][b] = zero;
  gemm128_mainloop(abf, wT, m0, n0, lds, acc);

  const int l = threadIdx.x & 63, w = threadIdx.x >> 6;
  const int wm = w >> 1, wn = w & 1;
#pragma unroll
  for (int nt = 0; nt < 4; ++nt) {
    int n = n0 + wn * 64 + nt * 16 + (l & 15);
    float bv = bias[n];
#pragma unroll
    for (int mt = 0; mt < 4; ++mt) {
#pragma unroll
      for (int r = 0; r < 4; ++r) {
        int m = m0 + wm * 64 + mt * 16 + ((l >> 4) << 2) + r;
        out[(size_t)m * D_ + n] = acc[mt][nt][r] + bv;
      }
    }
  }
}

// ---------------------------------------------------------------- attention
// grid: (B*NH) * (T/64). Block 256 thr = 4 waves; wave w owns q rows
// qb + w*16 .. +15. KV tiles of 64, staged fp32->bf16 into XOR-swizzled LDS.
__device__ __forceinline__ int swz8(int row, int chunk) {
  return (chunk ^ (row & 7)) << 3;  // element offset of 8-elem chunk
}

__global__ __launch_bounds__(256) void attn_fwd_kernel(
    const ushort_t* __restrict__ qbf, const float* __restrict__ kf,
    const float* __restrict__ vf, ushort_t* __restrict__ obf) {
  __shared__ ushort_t Kl[64 * 64];
  __shared__ ushort_t Vt[64 * 64];   // transposed: [dh][kv]
  __shared__ ushort_t Pl[4 * 16 * 64];
  const int bid = blockIdx.x;
  const int qt = bid & 31;
  const int bh = bid >> 5;           // b*NH + h
  const int qb = qt << 6;
  const int t = threadIdx.x, l = t & 63, w = t >> 6;

  const ushort_t* Qb = qbf + (size_t)bh * T_ * DH_;
  const float*    Kb = kf  + (size_t)bh * T_ * DH_;
  const float*    Vb = vf  + (size_t)bh * T_ * DH_;

  // Q fragments (A-operand): lane holds Q[qrow][(l>>4)*8 + j (+32)]
  const int qrow = qb + w * 16 + (l & 15);
  short8 aq[2];
  aq[0] = *(const short8*)&Qb[(size_t)qrow * DH_ + ((l >> 4) << 3)];
  aq[1] = *(const short8*)&Qb[(size_t)qrow * DH_ + ((l >> 4) << 3) + 32];

  f32x4 o[4];
  f32x4 zero = {0.f, 0.f, 0.f, 0.f};
#pragma unroll
  for (int nt = 0; nt < 4; ++nt) o[nt] = zero;
  float mrow[4], lrow[4];
#pragma unroll
  for (int r = 0; r < 4; ++r) { mrow[r] = -1e30f; lrow[r] = 0.f; }

  const float sc = 0.125f * 1.44269504f;  // /sqrt(64) folded into log2 domain
  const int nkv = (qb + 64) >> 6;

  for (int kt = 0; kt < nkv; ++kt) {
    const int kvb = kt << 6;
    // ---- stage K and V^T (fp32 -> bf16, XOR swizzle) ----
#pragma unroll
    for (int s = 0; s < 2; ++s) {
      int c = s * 256 + t;
      int row = c >> 3, col8 = c & 7;
      const float* ks = Kb + (size_t)(kvb + row) * DH_ + (col8 << 3);
      float4 k0 = *(const float4*)ks;
      float4 k1 = *(const float4*)(ks + 4);
      short8 kv8;
      kv8[0] = (short)f2bf(k0.x); kv8[1] = (short)f2bf(k0.y);
      kv8[2] = (short)f2bf(k0.z); kv8[3] = (short)f2bf(k0.w);
      kv8[4] = (short)f2bf(k1.x); kv8[5] = (short)f2bf(k1.y);
      kv8[6] = (short)f2bf(k1.z); kv8[7] = (short)f2bf(k1.w);
      *(short8*)&Kl[(row << 6) + swz8(row, col8)] = kv8;

      const float* vs = Vb + (size_t)(kvb + row) * DH_ + (col8 << 3);
      float4 v0 = *(const float4*)vs;
      float4 v1 = *(const float4*)(vs + 4);
      float vv[8] = {v0.x, v0.y, v0.z, v0.w, v1.x, v1.y, v1.z, v1.w};
#pragma unroll
      for (int j = 0; j < 8; ++j) {
        int dh = (col8 << 3) + j;
        Vt[(dh << 6) + swz8(dh, row >> 3) + (row & 7)] = f2bf(vv[j]);
      }
    }
    __syncthreads();

    // ---- S = Q K^T ----
    f32x4 s4[4];
#pragma unroll
    for (int nt = 0; nt < 4; ++nt) s4[nt] = zero;
#pragma unroll
    for (int nt = 0; nt < 4; ++nt) {
      int kvrow = (l & 15) + (nt << 4);
#pragma unroll
      for (int h2 = 0; h2 < 2; ++h2) {
        int chunk = (l >> 4) + (h2 << 2);
        short8 bk = *(const short8*)&Kl[(kvrow << 6) + swz8(kvrow, chunk)];
        s4[nt] = __builtin_amdgcn_mfma_f32_16x16x32_bf16(aq[h2], bk, s4[nt], 0, 0, 0);
      }
    }

    // ---- scale (+ causal mask on diagonal tiles) ----
    const int gq0 = qb + w * 16 + ((l >> 4) << 2);
    if (kvb + 63 > gq0) {  // wave-uniform enough; predicated inner
#pragma unroll
      for (int nt = 0; nt < 4; ++nt) {
        int gk = kvb + (nt << 4) + (l & 15);
#pragma unroll
        for (int r = 0; r < 4; ++r)
          s4[nt][r] = (gk <= gq0 + r) ? s4[nt][r] * sc : -1e30f;
      }
    } else {
#pragma unroll
      for (int nt = 0; nt < 4; ++nt)
#pragma unroll
        for (int r = 0; r < 4; ++r) s4[nt][r] *= sc;
    }

    // ---- online softmax (rows live in lanes l&15 = cols; reduce over 16) --
    ushort_t* Pw = &Pl[(w << 4) << 6];
#pragma unroll
    for (int r = 0; r < 4; ++r) {
      float mx = fmaxf(fmaxf(s4[0][r], s4[1][r]), fmaxf(s4[2][r], s4[3][r]));
      mx = fmaxf(mx, __shfl_xor(mx, 1));
      mx = fmaxf(mx, __shfl_xor(mx, 2));
      mx = fmaxf(mx, __shfl_xor(mx, 4));
      mx = fmaxf(mx, __shfl_xor(mx, 8));
      float mnew = fmaxf(mrow[r], mx);
      float corr = exp2f(mrow[r] - mnew);
      mrow[r] = mnew;
      float rs = 0.f;
#pragma unroll
      for (int nt = 0; nt < 4; ++nt) {
        float p = exp2f(s4[nt][r] - mnew);
        s4[nt][r] = p;
        rs += p;
      }
      rs += __shfl_xor(rs, 1);
      rs += __shfl_xor(rs, 2);
      rs += __shfl_xor(rs, 4);
      rs += __shfl_xor(rs, 8);
      lrow[r] = lrow[r] * corr + rs;
#pragma unroll
      for (int nt = 0; nt < 4; ++nt) o[nt][r] *= corr;
    }

    // ---- P -> LDS (bf16, swizzled), then PV ----
    const int prow0 = (l >> 4) << 2;
#pragma unroll
    for (int nt = 0; nt < 4; ++nt) {
      int col = (l & 15) + (nt << 4);
#pragma unroll
      for (int r = 0; r < 4; ++r)
        Pw[((prow0 + r) << 6) + swz8(prow0 + r, col >> 3) + (col & 7)] =
            f2bf(s4[nt][r]);
    }
#pragma unroll
    for (int h2 = 0; h2 < 2; ++h2) {
      int chunk = (l >> 4) + (h2 << 2);
      int prow = l & 15;
      short8 pa = *(const short8*)&Pw[(prow << 6) + swz8(prow, chunk)];
#pragma unroll
      for (int nt = 0; nt < 4; ++nt) {
        int dhrow = (l & 15) + (nt << 4);
        short8 bv = *(const short8*)&Vt[(dhrow << 6) + swz8(dhrow, chunk)];
        o[nt] = __builtin_amdgcn_mfma_f32_16x16x32_bf16(pa, bv, o[nt], 0, 0, 0);
      }
    }
    __syncthreads();
  }

  // ---- epilogue: O/l -> attn_bf [B][T][NH*DH] ----
  const int b = bh / NH_, h = bh - b * NH_;
#pragma unroll
  for (int r = 0; r < 4; ++r) {
    float inv = 1.f / lrow[r];
    int q = qb + w * 16 + ((l >> 4) << 2) + r;
#pragma unroll
    for (int nt = 0; nt < 4; ++nt) {
      int dh = (nt << 4) + (l & 15);
      obf[((size_t)(b * T_ + q)) * D_ + h * DH_ + dh] = f2bf(o[nt][r] * inv);
    }
  }
}

// ---------------------------------------------------------------- launch
extern "C" void kernel_launch(void* const* d_in, const int* in_sizes, int n_in,
                              void* d_out, int out_size, void* d_ws, size_t ws_size,
                              hipStream_t stream) {
  const float* x      = (const float*)d_in[0];
  const float* w_attn = (const float*)d_in[1];
  const float* b_attn = (const float*)d_in[2];
  const float* w_proj = (const float*)d_in[3];
  const float* b_proj = (const float*)d_in[4];

  float* out  = (float*)d_out;
  float* kout = out + (size_t)B_ * T_ * D_;        // 6291456
  float* vout = kout + (size_t)B_ * T_ * D_;       // 12582912

  char* ws = (char*)d_ws;
  ushort_t* xbf = (ushort_t*)(ws);                  // 12,582,912 B
  ushort_t* wTa = (ushort_t*)(ws + 12582912);       //  3,538,944 B
  ushort_t* wTp = (ushort_t*)(ws + 16121856);       //  1,179,648 B
  ushort_t* qbf = (ushort_t*)(ws + 17301504);       // 12,582,912 B
  ushort_t* abf = (ushort_t*)(ws + 29884416);       // 12,582,912 B

  cvt_bf16_vec<<<6144, 256, 0, stream>>>(x, xbf, (B_ * T_ * D_) / 4);
  dim3 tb(32, 8);
  transpose_cvt<<<dim3(72, 24), tb, 0, stream>>>(w_attn, wTa, D_, 3 * D_);
  transpose_cvt<<<dim3(24, 24), tb, 0, stream>>>(w_proj, wTp, D_, D_);

  gemm_qkv_kernel<<<64 * 18, 256, 0, stream>>>(xbf, wTa, b_attn, qbf, kout, vout);
  attn_fwd_kernel<<<B_ * NH_ * (T_ / 64), 256, 0, stream>>>(qbf, kout, vout, abf);
  gemm_proj_kernel<<<64 * 6, 256, 0, stream>>>(abf, wTp, b_proj, out);
}

// Round 2
// 223.571 us; speedup vs baseline: 1.5257x; 1.5257x over previous
//
#include <hip/hip_runtime.h>
#include <hip/hip_bf16.h>

typedef unsigned short ushort_t;
typedef __attribute__((ext_vector_type(8))) short short8;
typedef __attribute__((ext_vector_type(4))) float f32x4;

#define B_    4
#define T_    2048
#define D_    768
#define NH_   12
#define DH_   64
#define MTOT  8192    /* B*T */
#define KDIM  768

__device__ __forceinline__ ushort_t f2bf(float f) {
  union { float f; unsigned u; } c; c.f = f;
  unsigned u = c.u;
  return (ushort_t)((u + 0x7FFFu + ((u >> 16) & 1u)) >> 16);
}

__device__ __forceinline__ void gload_lds16(const void* g, void* l) {
  __builtin_amdgcn_global_load_lds(
      (const __attribute__((address_space(1))) unsigned int*)g,
      (__attribute__((address_space(3))) unsigned int*)l, 16, 0, 0);
}

// ---------------------------------------------------------------- converts
__global__ void cvt_bf16_vec(const float* __restrict__ in,
                             ushort_t* __restrict__ out, int n4) {
  int i = blockIdx.x * blockDim.x + threadIdx.x;
  if (i >= n4) return;
  float4 v = ((const float4*)in)[i];
  ushort4 o;
  o.x = f2bf(v.x); o.y = f2bf(v.y); o.z = f2bf(v.z); o.w = f2bf(v.w);
  ((ushort4*)out)[i] = o;
}

// in [R][C] fp32 -> out [C][R] bf16
__global__ void transpose_cvt(const float* __restrict__ in,
                              ushort_t* __restrict__ out, int R, int C) {
  __shared__ float tile[32][33];
  int c0 = blockIdx.x * 32, r0 = blockIdx.y * 32;
  int tx = threadIdx.x, ty = threadIdx.y;
#pragma unroll
  for (int j = 0; j < 32; j += 8)
    tile[ty + j][tx] = in[(size_t)(r0 + ty + j) * C + c0 + tx];
  __syncthreads();
#pragma unroll
  for (int j = 0; j < 32; j += 8)
    out[(size_t)(c0 + ty + j) * R + r0 + tx] = f2bf(tile[tx][ty + j]);
}

// ---------------------------------------------------------------- GEMM core
__device__ __forceinline__ void gemm128_mainloop(
    const ushort_t* __restrict__ A, const ushort_t* __restrict__ BT,
    int m0, int n0, ushort_t* lds, f32x4 acc[4][4]) {
  const int t = threadIdx.x;
  const int l = t & 63;
  const int w = t >> 6;
  const int wm = w >> 1, wn = w & 1;
  const int c0 = t, c1 = t + 256;
  const ushort_t* ga0 = A + (size_t)(m0 + (c0 >> 2)) * KDIM + ((c0 & 3) << 3);
  const ushort_t* ga1 = A + (size_t)(m0 + (c1 >> 2)) * KDIM + ((c1 & 3) << 3);
  const ushort_t* gb0 = BT + (size_t)(n0 + (c0 >> 2)) * KDIM + ((c0 & 3) << 3);
  const ushort_t* gb1 = BT + (size_t)(n0 + (c1 >> 2)) * KDIM + ((c1 & 3) << 3);
  ushort_t* la0 = lds + (0 * 256 + w * 64) * 8;
  ushort_t* la1 = lds + (1 * 256 + w * 64) * 8;
  ushort_t* lb0 = lds + 4096 + (0 * 256 + w * 64) * 8;
  ushort_t* lb1 = lds + 4096 + (1 * 256 + w * 64) * 8;
  const int frag_off = ((l & 15) * 32) + ((l >> 4) * 8);

  for (int k0 = 0; k0 < KDIM; k0 += 32) {
    gload_lds16(ga0 + k0, la0);
    gload_lds16(ga1 + k0, la1);
    gload_lds16(gb0 + k0, lb0);
    gload_lds16(gb1 + k0, lb1);
    __syncthreads();
    short8 af[4], bfv[4];
#pragma unroll
    for (int mt = 0; mt < 4; ++mt)
      af[mt] = *(const short8*)&lds[(wm * 64 + mt * 16) * 32 + frag_off];
#pragma unroll
    for (int nt = 0; nt < 4; ++nt)
      bfv[nt] = *(const short8*)&lds[4096 + (wn * 64 + nt * 16) * 32 + frag_off];
#pragma unroll
    for (int mt = 0; mt < 4; ++mt)
#pragma unroll
      for (int nt = 0; nt < 4; ++nt)
        acc[mt][nt] = __builtin_amdgcn_mfma_f32_16x16x32_bf16(
            af[mt], bfv[nt], acc[mt][nt], 0, 0, 0);
    __syncthreads();
  }
}

// GEMM1: x_bf [8192][768] @ wT_attn[2304][768]^T + b_attn
// sec0 -> q bf16 [bh][t][dh]; sec1 -> k fp32 (d_out) + k bf16 [bh][t][dh];
// sec2 -> v fp32 (d_out, [bh][t][dh]) + v^T bf16 [bh][dh][T].
__global__ __launch_bounds__(256) void gemm_qkv_kernel(
    const ushort_t* __restrict__ xbf, const ushort_t* __restrict__ wT,
    const float* __restrict__ bias, ushort_t* __restrict__ qbf,
    float* __restrict__ kout, float* __restrict__ vout,
    ushort_t* __restrict__ kbf, ushort_t* __restrict__ vtbf) {
  __shared__ ushort_t lds[8192];
  int bid = blockIdx.x;
  int m0 = (bid & 63) << 7;
  int n0 = (bid >> 6) << 7;
  f32x4 acc[4][4];
  f32x4 zero = {0.f, 0.f, 0.f, 0.f};
#pragma unroll
  for (int a = 0; a < 4; ++a)
#pragma unroll
    for (int b = 0; b < 4; ++b) acc[a][b] = zero;
  gemm128_mainloop(xbf, wT, m0, n0, lds, acc);

  const int l = threadIdx.x & 63, w = threadIdx.x >> 6;
  const int wm = w >> 1, wn = w & 1;
  const int sec = n0 / 768;
  const int b = m0 >> 11;
  const int tt_base = (m0 & 2047) + wm * 64;
#pragma unroll
  for (int nt = 0; nt < 4; ++nt) {
    int n = n0 + wn * 64 + nt * 16 + (l & 15);
    float bv = bias[n];
    int nn = n - sec * 768;
    int h = nn >> 6, dh = nn & 63;
    size_t head_base = ((size_t)(b * NH_ + h) * T_);
#pragma unroll
    for (int mt = 0; mt < 4; ++mt) {
      int tt0 = tt_base + mt * 16 + ((l >> 4) << 2);
      float vals[4];
#pragma unroll
      for (int r = 0; r < 4; ++r) vals[r] = acc[mt][nt][r] + bv;
      if (sec == 0) {
#pragma unroll
        for (int r = 0; r < 4; ++r)
          qbf[((head_base + tt0 + r) << 6) + dh] = f2bf(vals[r]);
      } else if (sec == 1) {
#pragma unroll
        for (int r = 0; r < 4; ++r) {
          size_t idx = ((head_base + tt0 + r) << 6) + dh;
          kout[idx] = vals[r];
          kbf[idx] = f2bf(vals[r]);
        }
      } else {
#pragma unroll
        for (int r = 0; r < 4; ++r)
          vout[((head_base + tt0 + r) << 6) + dh] = vals[r];
        ushort4 pk;
        pk.x = f2bf(vals[0]); pk.y = f2bf(vals[1]);
        pk.z = f2bf(vals[2]); pk.w = f2bf(vals[3]);
        *(ushort4*)&vtbf[((size_t)(b * NH_ + h) * DH_ + dh) * T_ + tt0] = pk;
      }
    }
  }
}

// GEMM2: attn_bf [8192][768] @ wT_proj[768][768]^T + b_proj -> out fp32
__global__ __launch_bounds__(256) void gemm_proj_kernel(
    const ushort_t* __restrict__ abf, const ushort_t* __restrict__ wT,
    const float* __restrict__ bias, float* __restrict__ out) {
  __shared__ ushort_t lds[8192];
  int bid = blockIdx.x;
  int m0 = (bid & 63) << 7;
  int n0 = (bid >> 6) << 7;
  f32x4 acc[4][4];
  f32x4 zero = {0.f, 0.f, 0.f, 0.f};
#pragma unroll
  for (int a = 0; a < 4; ++a)
#pragma unroll
    for (int b = 0; b < 4; ++b) acc[a][b] = zero;
  gemm128_mainloop(abf, wT, m0, n0, lds, acc);

  const int l = threadIdx.x & 63, w = threadIdx.x >> 6;
  const int wm = w >> 1, wn = w & 1;
#pragma unroll
  for (int nt = 0; nt < 4; ++nt) {
    int n = n0 + wn * 64 + nt * 16 + (l & 15);
    float bv = bias[n];
#pragma unroll
    for (int mt = 0; mt < 4; ++mt) {
#pragma unroll
      for (int r = 0; r < 4; ++r) {
        int m = m0 + wm * 64 + mt * 16 + ((l >> 4) << 2) + r;
        out[(size_t)m * D_ + n] = acc[mt][nt][r] + bv;
      }
    }
  }
}

// ---------------------------------------------------------------- attention
// 4 waves/block; wave w owns 32 q-rows [qb+32w, +32). KV tiles of 64 staged
// via global_load_lds (pre-swizzled src, linear LDS, swizzled reads).
// Deferred-max online softmax (THR=8, exp2 domain), lane-local deferred sum.
__global__ __launch_bounds__(256) void attn_fwd_kernel(
    const ushort_t* __restrict__ qbf, const ushort_t* __restrict__ kbf,
    const ushort_t* __restrict__ vtbf, ushort_t* __restrict__ obf) {
  __shared__ ushort_t Kl[2][4096];
  __shared__ ushort_t Vt[2][4096];
  __shared__ ushort_t Pl[4][2048];
  const int bid = blockIdx.x;
  const int qt = 15 - (bid & 15);       // heavy tiles first
  const int bh = bid >> 4;
  const int qb = qt << 7;
  const int t = threadIdx.x, l = t & 63, w = t >> 6;
  const int qw = qb + w * 32;

  const ushort_t* Qb = qbf + (size_t)bh * T_ * DH_;
  const ushort_t* Kb = kbf + (size_t)bh * T_ * DH_;
  const ushort_t* Vb = vtbf + (size_t)bh * DH_ * T_;

  // staging source addresses (pre-swizzled, m173 pattern)
  const int row0 = t >> 3, ch0 = t & 7;
  const int row1 = 32 + row0;
  const ushort_t* gK0 = Kb + row0 * DH_ + ((ch0 ^ (row0 & 7)) << 3);
  const ushort_t* gK1 = Kb + row1 * DH_ + ((ch0 ^ (row1 & 7)) << 3);
  const ushort_t* gV0 = Vb + (size_t)row0 * T_ + ((ch0 ^ (row0 & 7)) << 3);
  const ushort_t* gV1 = Vb + (size_t)row1 * T_ + ((ch0 ^ (row1 & 7)) << 3);

  // Q fragments: aq[f][h2]: lane l&15 = q row (frag f), k chunk (l>>4)*8+h2*32
  short8 aq[2][2];
#pragma unroll
  for (int f = 0; f < 2; ++f)
#pragma unroll
    for (int h2 = 0; h2 < 2; ++h2)
      aq[f][h2] = *(const short8*)&Qb[(size_t)(qw + f * 16 + (l & 15)) * DH_ +
                                      ((l >> 4) << 3) + h2 * 32];

  f32x4 o[2][4];
  f32x4 zero = {0.f, 0.f, 0.f, 0.f};
#pragma unroll
  for (int f = 0; f < 2; ++f)
#pragma unroll
    for (int nt = 0; nt < 4; ++nt) o[f][nt] = zero;
  float mrow[2][4], lpart[2][4];
#pragma unroll
  for (int f = 0; f < 2; ++f)
#pragma unroll
    for (int r = 0; r < 4; ++r) { mrow[f][r] = -1e30f; lpart[f][r] = 0.f; }

  const float sc = 0.125f * 1.44269504f;  // 1/sqrt(64) * log2(e)
  const int nkv = 2 * qt + 2;
  ushort_t* Pw = Pl[w];

  // prologue: stage tile 0 into buf 0
  gload_lds16(gK0, &Kl[0][w * 512]);
  gload_lds16(gK1, &Kl[0][2048 + w * 512]);
  gload_lds16(gV0, &Vt[0][w * 512]);
  gload_lds16(gV1, &Vt[0][2048 + w * 512]);
  __syncthreads();

  for (int kt = 0; kt < nkv; ++kt) {
    const int buf = kt & 1;
    const int kvb = kt << 6;
    if (kt + 1 < nkv) {  // prefetch next tile into other buffer
      const int nx = kt + 1;
      gload_lds16(gK0 + nx * 4096, &Kl[buf ^ 1][w * 512]);
      gload_lds16(gK1 + nx * 4096, &Kl[buf ^ 1][2048 + w * 512]);
      gload_lds16(gV0 + nx * 64,   &Vt[buf ^ 1][w * 512]);
      gload_lds16(gV1 + nx * 64,   &Vt[buf ^ 1][2048 + w * 512]);
    }
    if (kvb <= qw + 31) {  // wave has unmasked work in this tile
      // ---- S = Q K^T ----
      f32x4 s4[2][4];
#pragma unroll
      for (int f = 0; f < 2; ++f)
#pragma unroll
        for (int nt = 0; nt < 4; ++nt) s4[f][nt] = zero;
#pragma unroll
      for (int h2 = 0; h2 < 2; ++h2) {
#pragma unroll
        for (int nt = 0; nt < 4; ++nt) {
          int kr = (l & 15) + (nt << 4);
          int c = (l >> 4) + (h2 << 2);
          short8 bk = *(const short8*)&Kl[buf][(kr << 6) + ((c ^ (kr & 7)) << 3)];
          s4[0][nt] = __builtin_amdgcn_mfma_f32_16x16x32_bf16(aq[0][h2], bk, s4[0][nt], 0, 0, 0);
          s4[1][nt] = __builtin_amdgcn_mfma_f32_16x16x32_bf16(aq[1][h2], bk, s4[1][nt], 0, 0, 0);
        }
      }
      // ---- scale + causal mask ----
      const bool diag = (kvb + 63 > qw);
      if (diag) {
#pragma unroll
        for (int f = 0; f < 2; ++f) {
#pragma unroll
          for (int nt = 0; nt < 4; ++nt) {
            int gk = kvb + (nt << 4) + (l & 15);
#pragma unroll
            for (int r = 0; r < 4; ++r) {
              int gq = qw + f * 16 + ((l >> 4) << 2) + r;
              s4[f][nt][r] = (gk <= gq) ? s4[f][nt][r] * sc : -1e30f;
            }
          }
        }
      } else {
#pragma unroll
        for (int f = 0; f < 2; ++f)
#pragma unroll
          for (int nt = 0; nt < 4; ++nt)
#pragma unroll
            for (int r = 0; r < 4; ++r) s4[f][nt][r] *= sc;
      }
      // ---- deferred-max check (lane-local) ----
      float pm[2][4];
      bool ok = true;
#pragma unroll
      for (int f = 0; f < 2; ++f)
#pragma unroll
        for (int r = 0; r < 4; ++r) {
          pm[f][r] = fmaxf(fmaxf(s4[f][0][r], s4[f][1][r]),
                           fmaxf(s4[f][2][r], s4[f][3][r]));
          ok = ok && (pm[f][r] <= mrow[f][r] + 8.0f);
        }
      if (!__all(ok)) {  // rare: full reduce + rescale
#pragma unroll
        for (int f = 0; f < 2; ++f)
#pragma unroll
          for (int r = 0; r < 4; ++r) {
            float rm = pm[f][r];
            rm = fmaxf(rm, __shfl_xor(rm, 1));
            rm = fmaxf(rm, __shfl_xor(rm, 2));
            rm = fmaxf(rm, __shfl_xor(rm, 4));
            rm = fmaxf(rm, __shfl_xor(rm, 8));
            float mnew = fmaxf(mrow[f][r], rm);
            float corr = exp2f(mrow[f][r] - mnew);
            lpart[f][r] *= corr;
#pragma unroll
            for (int nt = 0; nt < 4; ++nt) o[f][nt][r] *= corr;
            mrow[f][r] = mnew;
          }
      }
      // ---- exp, lane-local sum, P -> LDS (swizzled bf16) ----
#pragma unroll
      for (int f = 0; f < 2; ++f) {
#pragma unroll
        for (int nt = 0; nt < 4; ++nt) {
#pragma unroll
          for (int r = 0; r < 4; ++r) {
            float p = exp2f(s4[f][nt][r] - mrow[f][r]);
            lpart[f][r] += p;
            int rq = f * 16 + ((l >> 4) << 2) + r;
            int kv = (nt << 4) + (l & 15);
            Pw[(rq << 6) + (((kv >> 3) ^ (rq & 7)) << 3) + (kv & 7)] = f2bf(p);
          }
        }
      }
      // ---- O += P V ----
#pragma unroll
      for (int k2 = 0; k2 < 2; ++k2) {
        int c = (l >> 4) + (k2 << 2);
        short8 pa[2], bvv[4];
#pragma unroll
        for (int f = 0; f < 2; ++f) {
          int rq = f * 16 + (l & 15);
          pa[f] = *(const short8*)&Pw[(rq << 6) + ((c ^ (rq & 7)) << 3)];
        }
#pragma unroll
        for (int nt = 0; nt < 4; ++nt) {
          int dr = (l & 15) + (nt << 4);
          bvv[nt] = *(const short8*)&Vt[buf][(dr << 6) + ((c ^ (dr & 7)) << 3)];
        }
#pragma unroll
        for (int f = 0; f < 2; ++f)
#pragma unroll
          for (int nt = 0; nt < 4; ++nt)
            o[f][nt] = __builtin_amdgcn_mfma_f32_16x16x32_bf16(pa[f], bvv[nt], o[f][nt], 0, 0, 0);
      }
    }
    __syncthreads();
  }

  // ---- final sum reduce + epilogue ----
  const int b = bh / NH_, h = bh - b * NH_;
#pragma unroll
  for (int f = 0; f < 2; ++f) {
#pragma unroll
    for (int r = 0; r < 4; ++r) {
      float s = lpart[f][r];
      s += __shfl_xor(s, 1);
      s += __shfl_xor(s, 2);
      s += __shfl_xor(s, 4);
      s += __shfl_xor(s, 8);
      float inv = 1.f / s;
      int q = qw + f * 16 + ((l >> 4) << 2) + r;
#pragma unroll
      for (int nt = 0; nt < 4; ++nt) {
        int dh = (nt << 4) + (l & 15);
        obf[((size_t)(b * T_ + q)) * D_ + h * DH_ + dh] = f2bf(o[f][nt][r] * inv);
      }
    }
  }
}

// ---------------------------------------------------------------- launch
extern "C" void kernel_launch(void* const* d_in, const int* in_sizes, int n_in,
                              void* d_out, int out_size, void* d_ws, size_t ws_size,
                              hipStream_t stream) {
  const float* x      = (const float*)d_in[0];
  const float* w_attn = (const float*)d_in[1];
  const float* b_attn = (const float*)d_in[2];
  const float* w_proj = (const float*)d_in[3];
  const float* b_proj = (const float*)d_in[4];

  float* out  = (float*)d_out;
  float* kout = out + (size_t)B_ * T_ * D_;
  float* vout = kout + (size_t)B_ * T_ * D_;

  char* ws = (char*)d_ws;
  ushort_t* xbf = (ushort_t*)(ws);                  // 12,582,912 B (reused as abf)
  ushort_t* wTa = (ushort_t*)(ws + 12582912);       //  3,538,944 B
  ushort_t* wTp = (ushort_t*)(ws + 16121856);       //  1,179,648 B
  ushort_t* qbf = (ushort_t*)(ws + 17301504);       // 12,582,912 B
  ushort_t* kbf = (ushort_t*)(ws + 29884416);       // 12,582,912 B
  ushort_t* vtbf = (ushort_t*)(ws + 42467328);      // 12,582,912 B
  ushort_t* abf = xbf;  // x_bf dead after GEMM1; alias for attention output

  cvt_bf16_vec<<<6144, 256, 0, stream>>>(x, xbf, (B_ * T_ * D_) / 4);
  dim3 tb(32, 8);
  transpose_cvt<<<dim3(72, 24), tb, 0, stream>>>(w_attn, wTa, D_, 3 * D_);
  transpose_cvt<<<dim3(24, 24), tb, 0, stream>>>(w_proj, wTp, D_, D_);

  gemm_qkv_kernel<<<64 * 18, 256, 0, stream>>>(xbf, wTa, b_attn, qbf, kout, vout,
                                               kbf, vtbf);
  attn_fwd_kernel<<<B_ * NH_ * (T_ / 128), 256, 0, stream>>>(qbf, kbf, vtbf, abf);
  gemm_proj_kernel<<<64 * 6, 256, 0, stream>>>(abf, wTp, b_proj, out);
}

// Round 3
// 147.439 us; speedup vs baseline: 2.3135x; 1.5164x over previous
//
#include <hip/hip_runtime.h>
#include <hip/hip_bf16.h>

typedef unsigned short ushort_t;
typedef __attribute__((ext_vector_type(8))) short short8;
typedef __attribute__((ext_vector_type(4))) float f32x4;

#define B_    4
#define T_    2048
#define D_    768
#define NH_   12
#define DH_   64
#define KDIM  768

__device__ __forceinline__ ushort_t f2bf(float f) {
  union { float f; unsigned u; } c; c.f = f;
  unsigned u = c.u;
  return (ushort_t)((u + 0x7FFFu + ((u >> 16) & 1u)) >> 16);
}

__device__ __forceinline__ unsigned cvt_pk_bf16(float lo, float hi) {
  unsigned r;
  asm("v_cvt_pk_bf16_f32 %0, %1, %2" : "=v"(r) : "v"(lo), "v"(hi));
  return r;
}

__device__ __forceinline__ void gload_lds16(const void* g, void* l) {
  __builtin_amdgcn_global_load_lds(
      (const __attribute__((address_space(1))) unsigned int*)g,
      (__attribute__((address_space(3))) unsigned int*)l, 16, 0, 0);
}

// ---------------------------------------------------------------- converts
__global__ void cvt_bf16_vec(const float* __restrict__ in,
                             ushort_t* __restrict__ out, int n4) {
  int i = blockIdx.x * blockDim.x + threadIdx.x;
  if (i >= n4) return;
  float4 v = ((const float4*)in)[i];
  ushort4 o;
  o.x = f2bf(v.x); o.y = f2bf(v.y); o.z = f2bf(v.z); o.w = f2bf(v.w);
  ((ushort4*)out)[i] = o;
}

// in [R][C] fp32 -> out [C][R] bf16
__global__ void transpose_cvt(const float* __restrict__ in,
                              ushort_t* __restrict__ out, int R, int C) {
  __shared__ float tile[32][33];
  int c0 = blockIdx.x * 32, r0 = blockIdx.y * 32;
  int tx = threadIdx.x, ty = threadIdx.y;
#pragma unroll
  for (int j = 0; j < 32; j += 8)
    tile[ty + j][tx] = in[(size_t)(r0 + ty + j) * C + c0 + tx];
  __syncthreads();
#pragma unroll
  for (int j = 0; j < 32; j += 8)
    out[(size_t)(c0 + ty + j) * R + r0 + tx] = f2bf(tile[tx][ty + j]);
}

// ---------------------------------------------------------------- GEMM core
__device__ __forceinline__ void gemm128_mainloop(
    const ushort_t* __restrict__ A, const ushort_t* __restrict__ BT,
    int m0, int n0, ushort_t* lds, f32x4 acc[4][4]) {
  const int t = threadIdx.x;
  const int l = t & 63;
  const int w = t >> 6;
  const int wm = w >> 1, wn = w & 1;
  const int c0 = t, c1 = t + 256;
  const ushort_t* ga0 = A + (size_t)(m0 + (c0 >> 2)) * KDIM + ((c0 & 3) << 3);
  const ushort_t* ga1 = A + (size_t)(m0 + (c1 >> 2)) * KDIM + ((c1 & 3) << 3);
  const ushort_t* gb0 = BT + (size_t)(n0 + (c0 >> 2)) * KDIM + ((c0 & 3) << 3);
  const ushort_t* gb1 = BT + (size_t)(n0 + (c1 >> 2)) * KDIM + ((c1 & 3) << 3);
  ushort_t* la0 = lds + (0 * 256 + w * 64) * 8;
  ushort_t* la1 = lds + (1 * 256 + w * 64) * 8;
  ushort_t* lb0 = lds + 4096 + (0 * 256 + w * 64) * 8;
  ushort_t* lb1 = lds + 4096 + (1 * 256 + w * 64) * 8;
  const int frag_off = ((l & 15) * 32) + ((l >> 4) * 8);

  for (int k0 = 0; k0 < KDIM; k0 += 32) {
    gload_lds16(ga0 + k0, la0);
    gload_lds16(ga1 + k0, la1);
    gload_lds16(gb0 + k0, lb0);
    gload_lds16(gb1 + k0, lb1);
    __syncthreads();
    short8 af[4], bfv[4];
#pragma unroll
    for (int mt = 0; mt < 4; ++mt)
      af[mt] = *(const short8*)&lds[(wm * 64 + mt * 16) * 32 + frag_off];
#pragma unroll
    for (int nt = 0; nt < 4; ++nt)
      bfv[nt] = *(const short8*)&lds[4096 + (wn * 64 + nt * 16) * 32 + frag_off];
#pragma unroll
    for (int mt = 0; mt < 4; ++mt)
#pragma unroll
      for (int nt = 0; nt < 4; ++nt)
        acc[mt][nt] = __builtin_amdgcn_mfma_f32_16x16x32_bf16(
            af[mt], bfv[nt], acc[mt][nt], 0, 0, 0);
    __syncthreads();
  }
}

// GEMM1: sec0 -> q bf16 (pre-scaled by 1/8*log2e); sec1 -> k fp32 + k bf16;
// sec2 -> v fp32 + v^T bf16 [bh][dh][T].
__global__ __launch_bounds__(256) void gemm_qkv_kernel(
    const ushort_t* __restrict__ xbf, const ushort_t* __restrict__ wT,
    const float* __restrict__ bias, ushort_t* __restrict__ qbf,
    float* __restrict__ kout, float* __restrict__ vout,
    ushort_t* __restrict__ kbf, ushort_t* __restrict__ vtbf) {
  __shared__ ushort_t lds[8192];
  int bid = blockIdx.x;
  int m0 = (bid & 63) << 7;
  int n0 = (bid >> 6) << 7;
  f32x4 acc[4][4];
  f32x4 zero = {0.f, 0.f, 0.f, 0.f};
#pragma unroll
  for (int a = 0; a < 4; ++a)
#pragma unroll
    for (int b = 0; b < 4; ++b) acc[a][b] = zero;
  gemm128_mainloop(xbf, wT, m0, n0, lds, acc);

  const float QSC = 0.125f * 1.44269504089f;
  const int l = threadIdx.x & 63, w = threadIdx.x >> 6;
  const int wm = w >> 1, wn = w & 1;
  const int sec = n0 / 768;
  const int b = m0 >> 11;
  const int tt_base = (m0 & 2047) + wm * 64;
#pragma unroll
  for (int nt = 0; nt < 4; ++nt) {
    int n = n0 + wn * 64 + nt * 16 + (l & 15);
    float bv = bias[n];
    int nn = n - sec * 768;
    int h = nn >> 6, dh = nn & 63;
    size_t head_base = ((size_t)(b * NH_ + h) * T_);
#pragma unroll
    for (int mt = 0; mt < 4; ++mt) {
      int tt0 = tt_base + mt * 16 + ((l >> 4) << 2);
      float vals[4];
#pragma unroll
      for (int r = 0; r < 4; ++r) vals[r] = acc[mt][nt][r] + bv;
      if (sec == 0) {
#pragma unroll
        for (int r = 0; r < 4; ++r)
          qbf[((head_base + tt0 + r) << 6) + dh] = f2bf(vals[r] * QSC);
      } else if (sec == 1) {
#pragma unroll
        for (int r = 0; r < 4; ++r) {
          size_t idx = ((head_base + tt0 + r) << 6) + dh;
          kout[idx] = vals[r];
          kbf[idx] = f2bf(vals[r]);
        }
      } else {
#pragma unroll
        for (int r = 0; r < 4; ++r)
          vout[((head_base + tt0 + r) << 6) + dh] = vals[r];
        ushort4 pk;
        pk.x = f2bf(vals[0]); pk.y = f2bf(vals[1]);
        pk.z = f2bf(vals[2]); pk.w = f2bf(vals[3]);
        *(ushort4*)&vtbf[((size_t)(b * NH_ + h) * DH_ + dh) * T_ + tt0] = pk;
      }
    }
  }
}

// GEMM2
__global__ __launch_bounds__(256) void gemm_proj_kernel(
    const ushort_t* __restrict__ abf, const ushort_t* __restrict__ wT,
    const float* __restrict__ bias, float* __restrict__ out) {
  __shared__ ushort_t lds[8192];
  int bid = blockIdx.x;
  int m0 = (bid & 63) << 7;
  int n0 = (bid >> 6) << 7;
  f32x4 acc[4][4];
  f32x4 zero = {0.f, 0.f, 0.f, 0.f};
#pragma unroll
  for (int a = 0; a < 4; ++a)
#pragma unroll
    for (int b = 0; b < 4; ++b) acc[a][b] = zero;
  gemm128_mainloop(abf, wT, m0, n0, lds, acc);

  const int l = threadIdx.x & 63, w = threadIdx.x >> 6;
  const int wm = w >> 1, wn = w & 1;
#pragma unroll
  for (int nt = 0; nt < 4; ++nt) {
    int n = n0 + wn * 64 + nt * 16 + (l & 15);
    float bv = bias[n];
#pragma unroll
    for (int mt = 0; mt < 4; ++mt) {
#pragma unroll
      for (int r = 0; r < 4; ++r) {
        int m = m0 + wm * 64 + mt * 16 + ((l >> 4) << 2) + r;
        out[(size_t)m * D_ + n] = acc[mt][nt][r] + bv;
      }
    }
  }
}

// ---------------------------------------------------------------- attention
// Balanced pair scheme: block handles q-strips j (lo) and 31-j (hi), 64 rows
// each (16/wave). hi iterates KV tiles 0..31-j, lo 0..j -> 33 compute-iters
// per block, KV staged once. Swapped QK^T (S^T in regs): lane owns one q-row
// per strip; softmax lane-local; P via 4x ds_write_b64 + 2x ds_read_b128.
__device__ __forceinline__ void strip_softmax_store(
    f32x4 s4[4], float& m, float& lp, f32x4 o[4], int qs, bool diag, int kvb,
    int g, int qi, char* pbase) {
  if (diag) {
    int gq = qs + qi;
#pragma unroll
    for (int nt = 0; nt < 4; ++nt)
#pragma unroll
      for (int r = 0; r < 4; ++r) {
        int gk = kvb + nt * 16 + g * 4 + r;
        if (gk > gq) s4[nt][r] = -1e30f;
      }
  }
  float pm = s4[0][0];
#pragma unroll
  for (int nt = 0; nt < 4; ++nt)
#pragma unroll
    for (int r = 0; r < 4; ++r) pm = fmaxf(pm, s4[nt][r]);
  bool ok = (pm <= m + 8.0f);
  if (!__all(ok)) {
    float rm = fmaxf(pm, __shfl_xor(pm, 16));
    rm = fmaxf(rm, __shfl_xor(rm, 32));
    float mn = fmaxf(m, rm);
    float c = exp2f(m - mn);
    lp *= c;
#pragma unroll
    for (int nt = 0; nt < 4; ++nt) o[nt] *= c;
    m = mn;
  }
#pragma unroll
  for (int nt = 0; nt < 4; ++nt) {
    float p0 = exp2f(s4[nt][0] - m);
    float p1 = exp2f(s4[nt][1] - m);
    float p2 = exp2f(s4[nt][2] - m);
    float p3 = exp2f(s4[nt][3] - m);
    lp += (p0 + p1) + (p2 + p3);
    uint2 pk;
    pk.x = cvt_pk_bf16(p0, p1);
    pk.y = cvt_pk_bf16(p2, p3);
    *(uint2*)(pbase + ((nt * 32 + g * 8) ^ ((qi & 7) << 4))) = pk;
  }
}

__global__ __launch_bounds__(256, 3) void attn_fwd_kernel(
    const ushort_t* __restrict__ qbf, const ushort_t* __restrict__ kbf,
    const ushort_t* __restrict__ vtbf, ushort_t* __restrict__ obf) {
  __shared__ ushort_t Kl[2][4096];
  __shared__ ushort_t Vt[2][4096];
  __shared__ ushort_t Pl[4][2][1024];
  const int bid = blockIdx.x;
  const int swz = (bid & 7) * 96 + (bid >> 3);   // 768 blocks, 8 XCDs
  const int jp = swz & 15;
  const int bh = swz >> 4;
  const int qlo = jp << 6, qhi = (31 - jp) << 6;
  const int lastH = 31 - jp, lastL = jp;
  const int t = threadIdx.x, l = t & 63, w = t >> 6;
  const int g = l >> 4, qi = l & 15;

  const ushort_t* Qb = qbf + (size_t)bh * T_ * DH_;
  const ushort_t* Kb = kbf + (size_t)bh * T_ * DH_;
  const ushort_t* Vb = vtbf + (size_t)bh * DH_ * T_;

  const int row0 = t >> 3, ch0 = t & 7, row1 = row0 + 32;
  const ushort_t* gK0 = Kb + row0 * DH_ + ((ch0 ^ (row0 & 7)) << 3);
  const ushort_t* gK1 = Kb + row1 * DH_ + ((ch0 ^ (row1 & 7)) << 3);
  const ushort_t* gV0 = Vb + (size_t)row0 * T_ + ((ch0 ^ (row0 & 7)) << 3);
  const ushort_t* gV1 = Vb + (size_t)row1 * T_ + ((ch0 ^ (row1 & 7)) << 3);

  short8 aqH[2], aqL[2];
  {
    const int qrH = qhi + w * 16 + qi, qrL = qlo + w * 16 + qi;
    aqH[0] = *(const short8*)&Qb[(size_t)qrH * DH_ + (g << 3)];
    aqH[1] = *(const short8*)&Qb[(size_t)qrH * DH_ + (g << 3) + 32];
    aqL[0] = *(const short8*)&Qb[(size_t)qrL * DH_ + (g << 3)];
    aqL[1] = *(const short8*)&Qb[(size_t)qrL * DH_ + (g << 3) + 32];
  }

  f32x4 oH[4], oL[4];
  f32x4 zero = {0.f, 0.f, 0.f, 0.f};
#pragma unroll
  for (int nt = 0; nt < 4; ++nt) { oH[nt] = zero; oL[nt] = zero; }
  float mH = -1e30f, lH = 0.f, mL = -1e30f, lL = 0.f;

  // prologue: stage tile 0 into buf 0
  gload_lds16(gK0, &Kl[0][w * 512]);
  gload_lds16(gK1, &Kl[0][2048 + w * 512]);
  gload_lds16(gV0, &Vt[0][w * 512]);
  gload_lds16(gV1, &Vt[0][2048 + w * 512]);
  __syncthreads();

  char* pbH = (char*)&Pl[w][0][0] + qi * 128;
  char* pbL = (char*)&Pl[w][1][0] + qi * 128;

  for (int kt = 0; kt <= lastH; ++kt) {
    const int buf = kt & 1;
    const int kvb = kt << 6;
    if (kt < lastH) {
      const int nx = kt + 1;
      gload_lds16(gK0 + nx * 4096, &Kl[buf ^ 1][w * 512]);
      gload_lds16(gK1 + nx * 4096, &Kl[buf ^ 1][2048 + w * 512]);
      gload_lds16(gV0 + nx * 64, &Vt[buf ^ 1][w * 512]);
      gload_lds16(gV1 + nx * 64, &Vt[buf ^ 1][2048 + w * 512]);
    }
    const bool loAct = (kt <= lastL);

    // ---- S^T = (K)(Q^T) for both strips (K-frags shared) ----
    f32x4 s4H[4], s4L[4];
#pragma unroll
    for (int nt = 0; nt < 4; ++nt) { s4H[nt] = zero; s4L[nt] = zero; }
#pragma unroll
    for (int h2 = 0; h2 < 2; ++h2) {
      short8 bk[4];
#pragma unroll
      for (int nt = 0; nt < 4; ++nt)
        bk[nt] = *(const short8*)&Kl[buf][((nt * 16 + qi) << 6) +
                                          (((g + 4 * h2) ^ (qi & 7)) << 3)];
#pragma unroll
      for (int nt = 0; nt < 4; ++nt)
        s4H[nt] = __builtin_amdgcn_mfma_f32_16x16x32_bf16(bk[nt], aqH[h2],
                                                          s4H[nt], 0, 0, 0);
      if (loAct) {
#pragma unroll
        for (int nt = 0; nt < 4; ++nt)
          s4L[nt] = __builtin_amdgcn_mfma_f32_16x16x32_bf16(bk[nt], aqL[h2],
                                                            s4L[nt], 0, 0, 0);
      }
    }

    // ---- softmax + P store (lane-local; S already scaled via Q) ----
    strip_softmax_store(s4H, mH, lH, oH, qhi + w * 16, kt == lastH, kvb,
                        g, qi, pbH);
    if (loAct)
      strip_softmax_store(s4L, mL, lL, oL, qlo + w * 16, kt == lastL, kvb,
                          g, qi, pbL);

    // ---- O^T += V^T P^T (V-frags shared) ----
#pragma unroll
    for (int k2 = 0; k2 < 2; ++k2) {
      short8 av[4];
#pragma unroll
      for (int nt = 0; nt < 4; ++nt)
        av[nt] = *(const short8*)&Vt[buf][((nt * 16 + qi) << 6) +
                                          (((g + 4 * k2) ^ (qi & 7)) << 3)];
      short8 pH = *(const short8*)(pbH + ((g * 16 + k2 * 64) ^ ((qi & 7) << 4)));
#pragma unroll
      for (int nt = 0; nt < 4; ++nt)
        oH[nt] = __builtin_amdgcn_mfma_f32_16x16x32_bf16(av[nt], pH, oH[nt],
                                                         0, 0, 0);
      if (loAct) {
        short8 pL = *(const short8*)(pbL + ((g * 16 + k2 * 64) ^ ((qi & 7) << 4)));
#pragma unroll
        for (int nt = 0; nt < 4; ++nt)
          oL[nt] = __builtin_amdgcn_mfma_f32_16x16x32_bf16(av[nt], pL, oL[nt],
                                                           0, 0, 0);
      }
    }
    __syncthreads();
  }

  // ---- epilogue ----
  const int b = bh / NH_, h = bh - b * NH_;
#pragma unroll
  for (int s = 0; s < 2; ++s) {
    float lp = s ? lL : lH;
    f32x4* o = s ? oL : oH;
    int qs = (s ? qlo : qhi) + w * 16 + qi;
    lp += __shfl_xor(lp, 16);
    lp += __shfl_xor(lp, 32);
    float inv = 1.f / lp;
    size_t rowb = (size_t)(b * T_ + qs) * D_ + h * DH_;
#pragma unroll
    for (int nt = 0; nt < 4; ++nt) {
      ushort4 pk;
      pk.x = f2bf(o[nt][0] * inv);
      pk.y = f2bf(o[nt][1] * inv);
      pk.z = f2bf(o[nt][2] * inv);
      pk.w = f2bf(o[nt][3] * inv);
      *(ushort4*)&obf[rowb + nt * 16 + g * 4] = pk;
    }
  }
}

// ---------------------------------------------------------------- launch
extern "C" void kernel_launch(void* const* d_in, const int* in_sizes, int n_in,
                              void* d_out, int out_size, void* d_ws, size_t ws_size,
                              hipStream_t stream) {
  const float* x      = (const float*)d_in[0];
  const float* w_attn = (const float*)d_in[1];
  const float* b_attn = (const float*)d_in[2];
  const float* w_proj = (const float*)d_in[3];
  const float* b_proj = (const float*)d_in[4];

  float* out  = (float*)d_out;
  float* kout = out + (size_t)B_ * T_ * D_;
  float* vout = kout + (size_t)B_ * T_ * D_;

  char* ws = (char*)d_ws;
  ushort_t* xbf = (ushort_t*)(ws);                  // reused as abf
  ushort_t* wTa = (ushort_t*)(ws + 12582912);
  ushort_t* wTp = (ushort_t*)(ws + 16121856);
  ushort_t* qbf = (ushort_t*)(ws + 17301504);
  ushort_t* kbf = (ushort_t*)(ws + 29884416);
  ushort_t* vtbf = (ushort_t*)(ws + 42467328);
  ushort_t* abf = xbf;

  cvt_bf16_vec<<<6144, 256, 0, stream>>>(x, xbf, (B_ * T_ * D_) / 4);
  dim3 tb(32, 8);
  transpose_cvt<<<dim3(72, 24), tb, 0, stream>>>(w_attn, wTa, D_, 3 * D_);
  transpose_cvt<<<dim3(24, 24), tb, 0, stream>>>(w_proj, wTp, D_, D_);

  gemm_qkv_kernel<<<64 * 18, 256, 0, stream>>>(xbf, wTa, b_attn, qbf, kout, vout,
                                               kbf, vtbf);
  attn_fwd_kernel<<<48 * 16, 256, 0, stream>>>(qbf, kbf, vtbf, abf);
  gemm_proj_kernel<<<64 * 6, 256, 0, stream>>>(abf, wTp, b_proj, out);
}